// Round 16
// baseline (223.674 us; speedup 1.0000x reference)
//
#include <hip/hip_runtime.h>
#include <hip/hip_bf16.h>

// ---------- types / helpers ----------
typedef unsigned short u16;
typedef short short8 __attribute__((ext_vector_type(8)));
typedef float f32x4 __attribute__((ext_vector_type(4)));
typedef float f32x16 __attribute__((ext_vector_type(16)));
typedef u16 u16x4 __attribute__((ext_vector_type(4)));

__device__ __forceinline__ u16 f2bf(float f) {
    unsigned int u = __float_as_uint(f);
    u += 0x7fffu + ((u >> 16) & 1u);   // round-to-nearest-even
    return (u16)(u >> 16);
}
__device__ __forceinline__ float bf2f(u16 s) {
    return __uint_as_float(((unsigned int)s) << 16);
}
// packs 2 f32 -> 2 bf16 (RNE); official intrinsic -> v_cvt_pk_bf16_f32
__device__ __forceinline__ unsigned pack2(float lo, float hi) {
    union { __hip_bfloat162 h; unsigned u; } cv;
    cv.h = __float22bfloat162_rn(make_float2(lo, hi));
    return cv.u;
}
__device__ __forceinline__ f32x4 mfma16(short8 a, short8 b, f32x4 c) {
    return __builtin_amdgcn_mfma_f32_16x16x32_bf16(a, b, c, 0, 0, 0);
}
__device__ __forceinline__ f32x16 mfma32(short8 a, short8 b, f32x16 c) {
    return __builtin_amdgcn_mfma_f32_32x32x16_bf16(a, b, c, 0, 0, 0);
}
// async global->LDS, 16B/lane; LDS dest = wave-uniform base + lane*16 (m97/m104)
__device__ __forceinline__ void gld16(const void* g, void* l) {
    __builtin_amdgcn_global_load_lds(
        (const __attribute__((address_space(1))) unsigned int*)g,
        (__attribute__((address_space(3))) unsigned int*)l, 16, 0, 0);
}

// ---------- constants ----------
#define BATCH 2
#define SEQ   2048
#define HID   2048
#define NH    8
#define HD    256
#define MROWS (BATCH * SEQ)   // 4096

// ---------- LDS-tiled weight transposes (4 matrices, 1 launch) ----------
// blockIdx.x: 0..31 Wq | 32..35 Wk | 36..39 Wv | 40..71 Wo;  blockIdx.y: k-tile.
__global__ __launch_bounds__(256) void k_wt(const float* __restrict__ Wq,
                                            const float* __restrict__ Wk,
                                            const float* __restrict__ Wv,
                                            const float* __restrict__ Wo,
                                            u16* __restrict__ Wqkvt,
                                            u16* __restrict__ Wot) {
    const int cx = blockIdx.x;
    const float* W; u16* Wt; int N, n0;
    if (cx < 32)      { W = Wq; Wt = Wqkvt;                       N = 2048; n0 = cx << 6; }
    else if (cx < 36) { W = Wk; Wt = Wqkvt + (size_t)2048 * 2048; N = 256;  n0 = (cx - 32) << 6; }
    else if (cx < 40) { W = Wv; Wt = Wqkvt + (size_t)2304 * 2048; N = 256;  n0 = (cx - 36) << 6; }
    else              { W = Wo; Wt = Wot;                         N = 2048; n0 = (cx - 40) << 6; }

    __shared__ float tile[64][65];   // +1 pad: conflict-free transposed read
    const int k0 = blockIdx.y << 6;
    const int tr = threadIdx.x >> 6, tc = threadIdx.x & 63;
#pragma unroll
    for (int i = 0; i < 16; i++)
        tile[i * 4 + tr][tc] = W[(size_t)(k0 + i * 4 + tr) * N + n0 + tc];
    __syncthreads();
#pragma unroll
    for (int i = 0; i < 16; i++) {
        int r = i * 4 + tr;
        Wt[(size_t)(n0 + r) * 2048 + k0 + tc] = f2bf(tile[tc][r]);
    }
}

// ---------- bf16 GEMM: m97 single-buffer + T2 both-sides swizzle ----------
// C = A[M,K] * Bt[N,K]^T; 128x128 tile, BK=64, 4 waves, XCD-chunked grid.
// FUSEQKV=1: A comes from fp32 `hidden` DIRECTLY — converted during staging
// (reg-stage 2x float4 -> cvt_pk -> ds_write_b128), eliminating the separate
// cvt pass. The write lands exactly where gld16 wrote: LDS[r][bc] =
// G[r][bc ^ (r&7)*16] (lane l: row=l>>3, bc=(l&7)*16, src col 8*((l&7)^(l>>3))).
// Live range is within the stage phase -> no cross-barrier VGPR holding (r14).
// B always via gld16 from the pre-transposed bf16 weights.
template<int FUSEQKV>
__global__ __launch_bounds__(256) void k_gemm(const u16* __restrict__ A16,
                                              const float* __restrict__ A32,
                                              const u16* __restrict__ Bt,
                                              u16* __restrict__ Cq,
                                              u16* __restrict__ Ckv,
                                              float* __restrict__ Cf,
                                              int K, int nbx) {
    const int cpx = gridDim.x >> 3;
    const int t8  = (blockIdx.x & 7) * cpx + (blockIdx.x >> 3);   // bijective (nwg%8==0)
    const int m0 = (t8 / nbx) << 7;
    const int n0 = (t8 % nbx) << 7;

    const int tid = threadIdx.x, lane = tid & 63, wave = tid >> 6;
    const int g = lane >> 4, c = lane & 15;
    const int wrow = (wave >> 1) << 6, wcol = (wave & 1) << 6;

    __shared__ __align__(16) u16 sA[128 * 64];
    __shared__ __align__(16) u16 sB[128 * 64];

    const int srow = lane >> 3;                      // 0..7 within 8-row DMA chunk
    const int scol = ((lane & 7) ^ srow) << 3;       // inverse swizzle on source
    const u16*   gA  = A16 + (size_t)(m0 + wave * 32 + srow) * K + scol;
    const float* gA3 = A32 + (size_t)(m0 + wave * 32 + srow) * K + scol;
    const u16*   gB  = Bt  + (size_t)(n0 + wave * 32 + srow) * K + scol;
    u16* const lA = sA + wave * 32 * 64;
    u16* const lB = sB + wave * 32 * 64;

    f32x4 acc[4][4] = {};

    for (int k0 = 0; k0 < K; k0 += 64) {
        __syncthreads();                  // prev tile fully consumed
#pragma unroll
        for (int i = 0; i < 4; i++) {
            if (FUSEQKV) {                // fp32 load + cvt + ds_write (fused cvt)
                const float* src = gA3 + k0 + (size_t)i * 8 * K;
                float4 f0 = *(const float4*)(src);
                float4 f1 = *(const float4*)(src + 4);
                uint4 pk;
                pk.x = pack2(f0.x, f0.y); pk.y = pack2(f0.z, f0.w);
                pk.z = pack2(f1.x, f1.y); pk.w = pack2(f1.z, f1.w);
                *(uint4*)((char*)(lA + i * 8 * 64) + lane * 16) = pk;
            } else {
                gld16(gA + k0 + (size_t)i * 8 * K, lA + i * 8 * 64);
            }
            gld16(gB + k0 + (size_t)i * 8 * K, lB + i * 8 * 64);
        }
        __syncthreads();                  // vmcnt+lgkmcnt drained before barrier
#pragma unroll
        for (int ks = 0; ks < 2; ks++) {
            short8 aF[4], bF[4];
#pragma unroll
            for (int tt = 0; tt < 4; tt++) {
                const int ar = wrow + tt * 16 + c;
                const int br = wcol + tt * 16 + c;
                const int coff = ks * 64 + g * 16;   // byte offset within 128B row
                aF[tt] = *(const short8*)((const char*)sA + ar * 128 + (coff ^ ((ar & 7) << 4)));
                bF[tt] = *(const short8*)((const char*)sB + br * 128 + (coff ^ ((br & 7) << 4)));
            }
#pragma unroll
            for (int mt = 0; mt < 4; mt++)
#pragma unroll
                for (int ntc = 0; ntc < 4; ntc++)
                    acc[mt][ntc] = mfma16(aF[mt], bF[ntc], acc[mt][ntc]);
        }
    }

#pragma unroll
    for (int mt = 0; mt < 4; mt++)
#pragma unroll
        for (int ntc = 0; ntc < 4; ntc++)
#pragma unroll
            for (int r = 0; r < 4; r++) {
                int row = m0 + wrow + mt * 16 + g * 4 + r;
                int col = n0 + wcol + ntc * 16 + c;
                float v = acc[mt][ntc][r];
                if (FUSEQKV) {
                    if (col < 2048) Cq [(size_t)row * 2048 + col] = f2bf(v);
                    else            Ckv[(size_t)row * 512 + (col - 2048)] = f2bf(v);
                } else {
                    Cf[(size_t)row * 2048 + col] = v;
                }
            }
}

// ---------- fused post-GEMM: RoPE x8 (blocks 0..2303) + V transform (2304..2559) ----------
__global__ __launch_bounds__(256) void k_post(u16* __restrict__ Qb,
                                              const u16* __restrict__ KVb,
                                              char* __restrict__ KS,
                                              char* __restrict__ VS) {
    __shared__ u16 sT[64][72];       // [kv][d], +8 pad (vt branch only)
    const int bx = blockIdx.x;
    if (bx < 2304) {                 // ---- RoPE, vectorized x8 ----
        int idx = bx * 256 + threadIdx.x;
        const int QG = MROWS * NH * 16;    // 524288 Q groups
        if (idx < QG) {
            int row  = idx >> 7;
            int rest = idx & 127;
            int h = rest >> 4, d0 = (rest & 15) << 3;
            u16* base = Qb + (size_t)row * HID + h * HD + d0;
            int pos = row & (SEQ - 1);
            short8 lo = *(const short8*)(base);
            short8 hi = *(const short8*)(base + 128);
            short8 olo, ohi;
#pragma unroll
            for (int j = 0; j < 8; j++) {
                int d = d0 + j;
                float invf = __expf(-(float)d * (9.2103403719761836f / 128.0f));
                float ang = (float)pos * invf;
                float sn, cs; __sincosf(ang, &sn, &cs);
                float x0 = bf2f((u16)lo[j]);
                float x1 = bf2f((u16)hi[j]);
                olo[j] = (short)f2bf(x0 * cs - x1 * sn);
                ohi[j] = (short)f2bf(x1 * cs + x0 * sn);
            }
            *(short8*)(base)       = olo;
            *(short8*)(base + 128) = ohi;
        } else {
            int j0 = idx - QG;             // 65536 K groups
            int row = j0 >> 4, d0 = (j0 & 15) << 3;
            const u16* src = KVb + (size_t)row * 512 + d0;
            int pos = row & (SEQ - 1);
            short8 lo = *(const short8*)(src);
            short8 hi = *(const short8*)(src + 128);
            short8 olo, ohi;
#pragma unroll
            for (int j = 0; j < 8; j++) {
                int d = d0 + j;
                float invf = __expf(-(float)d * (9.2103403719761836f / 128.0f));
                float ang = (float)pos * invf;
                float sn, cs; __sincosf(ang, &sn, &cs);
                float x0 = bf2f((u16)lo[j]);
                float x1 = bf2f((u16)hi[j]);
                olo[j] = (short)f2bf(x0 * cs - x1 * sn);
                ohi[j] = (short)f2bf(x1 * cs + x0 * sn);
            }
            int bb = row >> 11, sr = row & 2047;
            char* obase = KS + ((size_t)bb << 20) + (size_t)(sr >> 6) * 32768 + (sr & 63) * 512;
            int xr = (sr & 31) << 4;
            *(short8*)(obase + (((d0 << 1))       ^ xr)) = olo;
            *(short8*)(obase + (((d0 << 1) + 256) ^ xr)) = ohi;
        }
        return;
    }
    // ---- V transform: KVb V-half -> VS swizzled tiles ----
    const int bid = bx - 2304;
    const int b = bid >> 7, kvt = (bid >> 2) & 31, dc = bid & 3;
    const int tr = threadIdx.x >> 6, tc = threadIdx.x & 63;
#pragma unroll
    for (int i = 0; i < 16; i++) {
        int kv = i * 4 + tr;
        sT[kv][tc] = KVb[((size_t)(b * SEQ + kvt * 64 + kv) << 9) + 256 + (dc << 6) + tc];
    }
    __syncthreads();
    char* obase = VS + ((size_t)b << 20) + (size_t)kvt * 32768;
#pragma unroll
    for (int e = 0; e < 2; e++) {
        int u = threadIdx.x * 2 + e;          // 0..511
        int dl = u >> 3, kvc = u & 7;         // d-local, kv-chunk
        union { u16 h[8]; uint4 q; } pk;
#pragma unroll
        for (int j = 0; j < 8; j++) pk.h[j] = sT[kvc * 8 + j][dl];
        int byte = dl * 512 + ((((dc << 7) + (kvc << 4))) ^ ((dl & 31) << 4));
        *(uint4*)(obase + byte) = pk.q;
    }
}

// ---------- causal GQA flash attention — r10/r13 structure (101 µs, frozen) ----------
// 512 blocks x 4 waves. Waves {0,1}: q rows [qb,qb+32), kv halves 0/1;
// waves {2,3}: q rows [qb+32,qb+64). Pair q-tile a with 31-a across the two
// per-CU block slots (balanced: 33 tile-units per CU). K/V staged via gld16.
// NOTE (r14 post-mortem): T14 reg-staging spills here (o[8]=128 VGPR accum
// leaves no headroom) -> 5x scratch traffic. gld16 DMA is the right path.
__global__ __launch_bounds__(256, 2) void k_attn(const u16* __restrict__ Q,
                                                 const char* __restrict__ KS,
                                                 const char* __restrict__ VS,
                                                 u16* __restrict__ Oa) {
    const int tid  = threadIdx.x;
    const int lane = tid & 63;
    const int wave = tid >> 6;
    const int l31  = lane & 31;
    const int hv   = lane >> 5;

    const int bid   = blockIdx.x;
    const int bh    = bid & 15;
    const int qpair = (bid >> 4) & 15;
    const int qidx  = (bid >> 8) ? (31 - qpair) : qpair;  // pair long+short on a CU
    const int qb    = qidx << 6;
    const int b = bh >> 3, head = bh & 7;

    __shared__ __align__(16) char smem[66560];   // K 32K | V 32K | m,l 1K
    char*  const pK  = smem;
    char*  const pV  = smem + 32768;
    float* const sML = (float*)(smem + 65536);

    // Q fragments in registers: row qg, d = 16*ks + 8*hv + j
    const int qg = qb + ((wave >> 1) << 5) + l31;
    short8 qf[16];
    {
        const u16* qptr = Q + (size_t)(b * SEQ + qg) * HID + head * HD + (hv << 3);
#pragma unroll
        for (int ks = 0; ks < 16; ks++)
            qf[ks] = *(const short8*)(qptr + (ks << 4));
    }

    f32x16 o[8] = {};
    float m = -1e30f, l = 0.f;

    const char* kgb = KS + ((size_t)b << 20);
    const char* vgb = VS + ((size_t)b << 20);
    const int   kxor  = l31 << 4;
    const char* kbase = pK + (((wave & 1) << 5) + l31) * 512;

    const int nt = qidx + 1;
    for (int t = 0; t < nt; t++) {
        __syncthreads();                          // prev tile fully consumed
#pragma unroll
        for (int i = 0; i < 8; i++) {             // 32KB K + 32KB V, DMA
            int chunk = (i << 2) + wave;
            gld16(kgb + (size_t)t * 32768 + chunk * 1024 + lane * 16, pK + chunk * 1024);
            gld16(vgb + (size_t)t * 32768 + chunk * 1024 + lane * 16, pV + chunk * 1024);
        }
        __syncthreads();                          // vmcnt drained before use

        // ---- S^T = K Q^T (32 kv x 32 q), dual accumulator chains ----
        f32x16 sv0 = {}, sv1 = {};
#pragma unroll
        for (int ks = 0; ks < 16; ks += 2) {
            short8 kf0 = *(const short8*)(kbase + (((ks << 5) + (hv << 4)) ^ kxor));
            short8 kf1 = *(const short8*)(kbase + ((((ks + 1) << 5) + (hv << 4)) ^ kxor));
            sv0 = mfma32(kf0, qf[ks], sv0);
            sv1 = mfma32(kf1, qf[ks + 1], sv1);
        }
        f32x16 s = sv0 + sv1;

        // ---- in-lane softmax for q-col l31 (16 kv values/lane) ----
        float v[16];
        float mx = -3.0e38f;
        const bool diag = (t == nt - 1);
#pragma unroll
        for (int r = 0; r < 16; r++) {
            float x = s[r] * 0.0625f;
            if (diag) {
                int kvg = (t << 6) + ((wave & 1) << 5) + (r & 3) + ((r >> 2) << 3) + (hv << 2);
                if (kvg > qg) x = -3.0e38f;       // sentinel << m-init (-1e30)
            }
            v[r] = x;
            mx = fmaxf(mx, x);
        }
        mx = fmaxf(mx, __shfl_xor(mx, 32));
        if (!__all(mx <= m + 8.0f)) {             // T13 defer-rescale
            float mn = fmaxf(m, mx);
            float sc = __expf(m - mn);
            l *= sc;
#pragma unroll
            for (int r = 0; r < 16; r++) {
                float scr = __shfl(sc, (r & 3) + ((r >> 2) << 3) + (hv << 2));
#pragma unroll
                for (int dt = 0; dt < 8; dt++) o[dt][r] *= scr;
            }
            m = mn;
        }
        float rs = 0.f;
#pragma unroll
        for (int r = 0; r < 16; r++) { v[r] = __expf(v[r] - m); rs += v[r]; }
        rs += __shfl_xor(rs, 32);
        l += rs;

        // ---- P -> A-fragments in-register (cvt_pk + half-exchange) ----
        unsigned wd[8], pw[8];
#pragma unroll
        for (int i = 0; i < 8; i++) wd[i] = pack2(v[2 * i], v[2 * i + 1]);
#pragma unroll
        for (int i = 0; i < 8; i++) pw[i] = (unsigned)__shfl_xor((int)wd[i], 32);

#pragma unroll
        for (int ks2 = 0; ks2 < 2; ks2++) {
            union { unsigned u[4]; short8 s8; } fr;
            const int o4 = ks2 << 2;
            fr.u[0] = hv ? pw[o4 + 2] : wd[o4 + 0];
            fr.u[1] = hv ? pw[o4 + 3] : wd[o4 + 1];
            fr.u[2] = hv ? wd[o4 + 2] : pw[o4 + 0];
            fr.u[3] = hv ? wd[o4 + 3] : pw[o4 + 1];
            const int vcol = ((wave & 1) << 6) + (ks2 << 5) + (hv << 4);
#pragma unroll
            for (int dt = 0; dt < 8; dt++) {
                int row  = ((dt & 1) << 5) + l31;
                int colb = ((dt >> 1) << 7) + vcol;
                short8 vf = *(const short8*)(pV + row * 512 + (colb ^ kxor));
                o[dt] = mfma32(fr.s8, vf, o[dt]);
            }
        }
    }

    // ---- merge the two kv-half softmaxes of each q-group ----
    __syncthreads();
    if (lane < 32) {
        sML[(wave << 6) + (l31 << 1)]     = m;
        sML[(wave << 6) + (l31 << 1) + 1] = l;
    }
    __syncthreads();
    float m1 = sML[((wave ^ 1) << 6) + (l31 << 1)];
    float l1 = sML[((wave ^ 1) << 6) + (l31 << 1) + 1];
    float M  = fmaxf(m, m1);
    float e0 = __expf(m - M), e1 = __expf(m1 - M);
    float fac = e0 / (l * e0 + l1 * e1);          // own-scale / combined-denominator
    float facr[16];
#pragma unroll
    for (int r = 0; r < 16; r++)
        facr[r] = __shfl(fac, (r & 3) + ((r >> 2) << 3) + (hv << 2));
#pragma unroll
    for (int dt = 0; dt < 8; dt++)
#pragma unroll
        for (int r = 0; r < 16; r++) o[dt][r] *= facr[r];

    float* sO = (float*)smem;                     // reuse K/V space: [pair][32q][256d]
    if (wave & 1) {
#pragma unroll
        for (int dt = 0; dt < 8; dt++)
#pragma unroll
            for (int r = 0; r < 16; r++) {
                int q = (r & 3) + ((r >> 2) << 3) + (hv << 2);
                sO[((wave >> 1) << 13) + (q << 8) + (dt << 5) + l31] = o[dt][r];
            }
    }
    __syncthreads();
    if (!(wave & 1)) {
#pragma unroll
        for (int dt = 0; dt < 8; dt++)
#pragma unroll
            for (int r = 0; r < 16; r++) {
                int q = (r & 3) + ((r >> 2) << 3) + (hv << 2);
                float val = o[dt][r] + sO[((wave >> 1) << 13) + (q << 8) + (dt << 5) + l31];
                Oa[(size_t)(b * SEQ + qb + ((wave >> 1) << 5) + q) * HID
                   + head * HD + (dt << 5) + l31] = f2bf(val);
            }
    }
}

// ---------- launch ----------
extern "C" void kernel_launch(void* const* d_in, const int* in_sizes, int n_in,
                              void* d_out, int out_size, void* d_ws, size_t ws_size,
                              hipStream_t stream) {
    const float* hidden = (const float*)d_in[0];
    // d_in[1] = attention_mask: pure causal, applied analytically (exp(-1e9) == 0)
    const float* Wq = (const float*)d_in[2];
    const float* Wk = (const float*)d_in[3];
    const float* Wv = (const float*)d_in[4];
    const float* Wo = (const float*)d_in[5];
    float* out = (float*)d_out;

    char* ws = (char*)d_ws;
    u16* Wqkvt  = (u16*)(ws + (16u << 20));         // 10 MB fused [2560][2048]
    u16* Wot    = (u16*)(ws + (26u << 20));         //  8 MB
    u16* Qb     = (u16*)(ws + (34u << 20));         // 16 MB
    u16* KVb    = (u16*)(ws + (50u << 20));         //  4 MB
    u16* Ab     = (u16*)(ws + (54u << 20));         // 16 MB (end 70 MB)
    char* KS    = ws;                               //  2 MB swizzled K tiles
    char* VS    = ws + (2u << 20);                  //  2 MB swizzled V tiles

    // weight transposes only (cvt now fused into the QKV GEMM A-staging)
    k_wt<<<dim3(72, 32), 256, 0, stream>>>(Wq, Wk, Wv, Wo, Wqkvt, Wot);

    // fused QKV projection reading fp32 hidden directly: N = 2560, grid 640
    k_gemm<1><<<640, 256, 0, stream>>>(nullptr, hidden, Wqkvt, Qb, KVb, nullptr, 2048, 20);

    k_post<<<2560, 256, 0, stream>>>(Qb, KVb, KS, VS);   // rope + V transform

    k_attn<<<512, 256, 0, stream>>>(Qb, KS, VS, Ab);

    // output projection (fp32 out, A = Ab bf16 via gld16): grid 512
    k_gemm<0><<<512, 256, 0, stream>>>(Ab, nullptr, Wot, nullptr, nullptr, out, 2048, 16);
}

// Round 17
// 221.641 us; speedup vs baseline: 1.0092x; 1.0092x over previous
//
#include <hip/hip_runtime.h>
#include <hip/hip_bf16.h>

// ---------- types / helpers ----------
typedef unsigned short u16;
typedef short short8 __attribute__((ext_vector_type(8)));
typedef float f32x4 __attribute__((ext_vector_type(4)));
typedef float f32x16 __attribute__((ext_vector_type(16)));
typedef u16 u16x4 __attribute__((ext_vector_type(4)));

__device__ __forceinline__ u16 f2bf(float f) {
    unsigned int u = __float_as_uint(f);
    u += 0x7fffu + ((u >> 16) & 1u);   // round-to-nearest-even
    return (u16)(u >> 16);
}
__device__ __forceinline__ float bf2f(u16 s) {
    return __uint_as_float(((unsigned int)s) << 16);
}
// packs 2 f32 -> 2 bf16 (RNE); official intrinsic -> v_cvt_pk_bf16_f32
__device__ __forceinline__ unsigned pack2(float lo, float hi) {
    union { __hip_bfloat162 h; unsigned u; } cv;
    cv.h = __float22bfloat162_rn(make_float2(lo, hi));
    return cv.u;
}
__device__ __forceinline__ f32x4 mfma16(short8 a, short8 b, f32x4 c) {
    return __builtin_amdgcn_mfma_f32_16x16x32_bf16(a, b, c, 0, 0, 0);
}
__device__ __forceinline__ f32x16 mfma32(short8 a, short8 b, f32x16 c) {
    return __builtin_amdgcn_mfma_f32_32x32x16_bf16(a, b, c, 0, 0, 0);
}
// async global->LDS, 16B/lane; LDS dest = wave-uniform base + lane*16 (m97/m104)
__device__ __forceinline__ void gld16(const void* g, void* l) {
    __builtin_amdgcn_global_load_lds(
        (const __attribute__((address_space(1))) unsigned int*)g,
        (__attribute__((address_space(3))) unsigned int*)l, 16, 0, 0);
}

// ---------- constants ----------
#define BATCH 2
#define SEQ   2048
#define HID   2048
#define NH    8
#define HD    256
#define MROWS (BATCH * SEQ)   // 4096

// ---------- fused preprocessing: hidden cvt (blocks 0..8191) + 4 weight ----------
// transposes (blocks 8192..10495; idx%72 selects matrix/col-tile, idx/72 k-tile)
__global__ __launch_bounds__(256) void k_prep(const float* __restrict__ hidden,
                                              u16* __restrict__ hid_bf,
                                              const float* __restrict__ Wq,
                                              const float* __restrict__ Wk,
                                              const float* __restrict__ Wv,
                                              const float* __restrict__ Wo,
                                              u16* __restrict__ Wqkvt,
                                              u16* __restrict__ Wot) {
    __shared__ float tile[64][65];   // +1 pad (unused in cvt branch)
    const int bx = blockIdx.x;
    if (bx < 8192) {                 // ---- fp32 -> bf16 convert, x4 ----
        int i = (bx * 256 + threadIdx.x) * 4;
        float4 v = *(const float4*)(hidden + i);
        u16x4 o; o.x = f2bf(v.x); o.y = f2bf(v.y); o.z = f2bf(v.z); o.w = f2bf(v.w);
        *(u16x4*)(hid_bf + i) = o;
        return;
    }
    const int idx = bx - 8192;       // ---- LDS-tiled weight transpose ----
    const int cx = idx % 72, ky = idx / 72;
    const float* W; u16* Wt; int N, n0;
    if (cx < 32)      { W = Wq; Wt = Wqkvt;                       N = 2048; n0 = cx << 6; }
    else if (cx < 36) { W = Wk; Wt = Wqkvt + (size_t)2048 * 2048; N = 256;  n0 = (cx - 32) << 6; }
    else if (cx < 40) { W = Wv; Wt = Wqkvt + (size_t)2304 * 2048; N = 256;  n0 = (cx - 36) << 6; }
    else              { W = Wo; Wt = Wot;                         N = 2048; n0 = (cx - 40) << 6; }
    const int k0 = ky << 6;
    const int tr = threadIdx.x >> 6, tc = threadIdx.x & 63;
#pragma unroll
    for (int i = 0; i < 16; i++)
        tile[i * 4 + tr][tc] = W[(size_t)(k0 + i * 4 + tr) * N + n0 + tc];
    __syncthreads();
#pragma unroll
    for (int i = 0; i < 16; i++) {
        int r = i * 4 + tr;
        Wt[(size_t)(n0 + r) * 2048 + k0 + tc] = f2bf(tile[tc][r]);
    }
}

// ---------- bf16 GEMM: m97-faithful SINGLE-buffer + T2 both-sides swizzle ----------
// (r12/r15, frozen) C = A[M,K] * Bt[N,K]^T; 128x128 tile, BK=64, 4 waves.
// NOTE (r16 post-mortem): fusing fp32->bf16 A-conversion into staging costs
// more than the separate cvt pass saves (reg roundtrip + ds_write in the
// serial stage phase). Pure gld16 staging is the right path.
template<int FUSEQKV>
__global__ __launch_bounds__(256) void k_gemm(const u16* __restrict__ A,
                                              const u16* __restrict__ Bt,
                                              u16* __restrict__ Cq,
                                              u16* __restrict__ Ckv,
                                              float* __restrict__ Cf,
                                              int K, int nbx) {
    const int cpx = gridDim.x >> 3;
    const int t8  = (blockIdx.x & 7) * cpx + (blockIdx.x >> 3);   // bijective (nwg%8==0)
    const int m0 = (t8 / nbx) << 7;
    const int n0 = (t8 % nbx) << 7;

    const int tid = threadIdx.x, lane = tid & 63, wave = tid >> 6;
    const int g = lane >> 4, c = lane & 15;
    const int wrow = (wave >> 1) << 6, wcol = (wave & 1) << 6;

    __shared__ __align__(16) u16 sA[128 * 64];
    __shared__ __align__(16) u16 sB[128 * 64];

    const int srow = lane >> 3;                      // 0..7 within 8-row DMA chunk
    const int scol = ((lane & 7) ^ srow) << 3;       // inverse swizzle on source
    const u16* gA = A  + (size_t)(m0 + wave * 32 + srow) * K + scol;
    const u16* gB = Bt + (size_t)(n0 + wave * 32 + srow) * K + scol;
    u16* const lA = sA + wave * 32 * 64;
    u16* const lB = sB + wave * 32 * 64;

    f32x4 acc[4][4] = {};

    for (int k0 = 0; k0 < K; k0 += 64) {
        __syncthreads();                  // prev tile fully consumed
#pragma unroll
        for (int i = 0; i < 4; i++) {
            gld16(gA + k0 + (size_t)i * 8 * K, lA + i * 8 * 64);
            gld16(gB + k0 + (size_t)i * 8 * K, lB + i * 8 * 64);
        }
        __syncthreads();                  // compiler drains vmcnt before barrier
#pragma unroll
        for (int ks = 0; ks < 2; ks++) {
            short8 aF[4], bF[4];
#pragma unroll
            for (int tt = 0; tt < 4; tt++) {
                const int ar = wrow + tt * 16 + c;
                const int br = wcol + tt * 16 + c;
                const int coff = ks * 64 + g * 16;   // byte offset within 128B row
                aF[tt] = *(const short8*)((const char*)sA + ar * 128 + (coff ^ ((ar & 7) << 4)));
                bF[tt] = *(const short8*)((const char*)sB + br * 128 + (coff ^ ((br & 7) << 4)));
            }
#pragma unroll
            for (int mt = 0; mt < 4; mt++)
#pragma unroll
                for (int ntc = 0; ntc < 4; ntc++)
                    acc[mt][ntc] = mfma16(aF[mt], bF[ntc], acc[mt][ntc]);
        }
    }

#pragma unroll
    for (int mt = 0; mt < 4; mt++)
#pragma unroll
        for (int ntc = 0; ntc < 4; ntc++)
#pragma unroll
            for (int r = 0; r < 4; r++) {
                int row = m0 + wrow + mt * 16 + g * 4 + r;
                int col = n0 + wcol + ntc * 16 + c;
                float v = acc[mt][ntc][r];
                if (FUSEQKV) {
                    if (col < 2048) Cq [(size_t)row * 2048 + col] = f2bf(v);
                    else            Ckv[(size_t)row * 512 + (col - 2048)] = f2bf(v);
                } else {
                    Cf[(size_t)row * 2048 + col] = v;
                }
            }
}

// ---------- post-GEMM: K-RoPE x8 (blocks 0..255) + V transform (256..511) ----------
// Q-RoPE now runs in-register inside k_attn (its qf fragments hold both
// halves of every RoPE pair) — removes 32 MB of Qb read+write traffic.
__global__ __launch_bounds__(256) void k_post(const u16* __restrict__ KVb,
                                              char* __restrict__ KS,
                                              char* __restrict__ VS) {
    __shared__ u16 sT[64][72];       // [kv][d], +8 pad (vt branch only)
    const int bx = blockIdx.x;
    if (bx < 256) {                  // ---- K-RoPE, vectorized x8 ----
        int idx = bx * 256 + threadIdx.x;      // 65536 K groups
        int row = idx >> 4, d0 = (idx & 15) << 3;
        const u16* src = KVb + (size_t)row * 512 + d0;
        int pos = row & (SEQ - 1);
        short8 lo = *(const short8*)(src);
        short8 hi = *(const short8*)(src + 128);
        short8 olo, ohi;
#pragma unroll
        for (int j = 0; j < 8; j++) {
            int d = d0 + j;
            float invf = __expf(-(float)d * (9.2103403719761836f / 128.0f));
            float ang = (float)pos * invf;
            float sn, cs; __sincosf(ang, &sn, &cs);
            float x0 = bf2f((u16)lo[j]);
            float x1 = bf2f((u16)hi[j]);
            olo[j] = (short)f2bf(x0 * cs - x1 * sn);
            ohi[j] = (short)f2bf(x1 * cs + x0 * sn);
        }
        int bb = row >> 11, sr = row & 2047;
        char* obase = KS + ((size_t)bb << 20) + (size_t)(sr >> 6) * 32768 + (sr & 63) * 512;
        int xr = (sr & 31) << 4;
        *(short8*)(obase + (((d0 << 1))       ^ xr)) = olo;
        *(short8*)(obase + (((d0 << 1) + 256) ^ xr)) = ohi;
        return;
    }
    // ---- V transform: KVb V-half -> VS swizzled tiles ----
    const int bid = bx - 256;
    const int b = bid >> 7, kvt = (bid >> 2) & 31, dc = bid & 3;
    const int tr = threadIdx.x >> 6, tc = threadIdx.x & 63;
#pragma unroll
    for (int i = 0; i < 16; i++) {
        int kv = i * 4 + tr;
        sT[kv][tc] = KVb[((size_t)(b * SEQ + kvt * 64 + kv) << 9) + 256 + (dc << 6) + tc];
    }
    __syncthreads();
    char* obase = VS + ((size_t)b << 20) + (size_t)kvt * 32768;
#pragma unroll
    for (int e = 0; e < 2; e++) {
        int u = threadIdx.x * 2 + e;          // 0..511
        int dl = u >> 3, kvc = u & 7;         // d-local, kv-chunk
        union { u16 h[8]; uint4 q; } pk;
#pragma unroll
        for (int j = 0; j < 8; j++) pk.h[j] = sT[kvc * 8 + j][dl];
        int byte = dl * 512 + ((((dc << 7) + (kvc << 4))) ^ ((dl & 31) << 4));
        *(uint4*)(obase + byte) = pk.q;
    }
}

// ---------- causal GQA flash attention — r10/r13 structure + in-register Q-RoPE ----------
// 512 blocks x 4 waves; pair q-tile a with 31-a per CU (balanced 33 units).
// Q fragments qf[ks][j] hold d = 16ks+8hv+j; the RoPE pair (d, d+128) for
// d<128 (ks<8) is qf[ks+8][j] in the SAME lane -> rotate in registers once
// in the prologue (identical f2bf rounding to the old memory path).
__global__ __launch_bounds__(256, 2) void k_attn(const u16* __restrict__ Q,
                                                 const char* __restrict__ KS,
                                                 const char* __restrict__ VS,
                                                 u16* __restrict__ Oa) {
    const int tid  = threadIdx.x;
    const int lane = tid & 63;
    const int wave = tid >> 6;
    const int l31  = lane & 31;
    const int hv   = lane >> 5;

    const int bid   = blockIdx.x;
    const int bh    = bid & 15;
    const int qpair = (bid >> 4) & 15;
    const int qidx  = (bid >> 8) ? (31 - qpair) : qpair;  // pair long+short on a CU
    const int qb    = qidx << 6;
    const int b = bh >> 3, head = bh & 7;

    __shared__ __align__(16) char smem[66560];   // K 32K | V 32K | m,l 1K
    char*  const pK  = smem;
    char*  const pV  = smem + 32768;
    float* const sML = (float*)(smem + 65536);

    // Q fragments in registers: row qg, d = 16*ks + 8*hv + j
    const int qg = qb + ((wave >> 1) << 5) + l31;
    short8 qf[16];
    {
        const u16* qptr = Q + (size_t)(b * SEQ + qg) * HID + head * HD + (hv << 3);
#pragma unroll
        for (int ks = 0; ks < 16; ks++)
            qf[ks] = *(const short8*)(qptr + (ks << 4));
    }
    // ---- in-register Q-RoPE (pos = qg; pair qf[ks][j] <-> qf[ks+8][j]) ----
#pragma unroll
    for (int ks = 0; ks < 8; ks++) {
#pragma unroll
        for (int j = 0; j < 8; j++) {
            int d = ks * 16 + (hv << 3) + j;            // 0..127
            float invf = __expf(-(float)d * (9.2103403719761836f / 128.0f));
            float ang = (float)qg * invf;
            float sn, cs; __sincosf(ang, &sn, &cs);
            float x0 = bf2f((u16)qf[ks][j]);
            float x1 = bf2f((u16)qf[ks + 8][j]);
            qf[ks][j]     = (short)f2bf(x0 * cs - x1 * sn);
            qf[ks + 8][j] = (short)f2bf(x1 * cs + x0 * sn);
        }
    }

    f32x16 o[8] = {};
    float m = -1e30f, l = 0.f;

    const char* kgb = KS + ((size_t)b << 20);
    const char* vgb = VS + ((size_t)b << 20);
    const int   kxor  = l31 << 4;
    const char* kbase = pK + (((wave & 1) << 5) + l31) * 512;

    const int nt = qidx + 1;
    for (int t = 0; t < nt; t++) {
        __syncthreads();                          // prev tile fully consumed
#pragma unroll
        for (int i = 0; i < 8; i++) {             // 32KB K + 32KB V, DMA
            int chunk = (i << 2) + wave;
            gld16(kgb + (size_t)t * 32768 + chunk * 1024 + lane * 16, pK + chunk * 1024);
            gld16(vgb + (size_t)t * 32768 + chunk * 1024 + lane * 16, pV + chunk * 1024);
        }
        __syncthreads();                          // vmcnt drained before use

        // ---- S^T = K Q^T (32 kv x 32 q), dual accumulator chains ----
        f32x16 sv0 = {}, sv1 = {};
#pragma unroll
        for (int ks = 0; ks < 16; ks += 2) {
            short8 kf0 = *(const short8*)(kbase + (((ks << 5) + (hv << 4)) ^ kxor));
            short8 kf1 = *(const short8*)(kbase + ((((ks + 1) << 5) + (hv << 4)) ^ kxor));
            sv0 = mfma32(kf0, qf[ks], sv0);
            sv1 = mfma32(kf1, qf[ks + 1], sv1);
        }
        f32x16 s = sv0 + sv1;

        // ---- in-lane softmax for q-col l31 (16 kv values/lane) ----
        float v[16];
        float mx = -3.0e38f;
        const bool diag = (t == nt - 1);
#pragma unroll
        for (int r = 0; r < 16; r++) {
            float x = s[r] * 0.0625f;
            if (diag) {
                int kvg = (t << 6) + ((wave & 1) << 5) + (r & 3) + ((r >> 2) << 3) + (hv << 2);
                if (kvg > qg) x = -3.0e38f;       // sentinel << m-init (-1e30)
            }
            v[r] = x;
            mx = fmaxf(mx, x);
        }
        mx = fmaxf(mx, __shfl_xor(mx, 32));
        if (!__all(mx <= m + 8.0f)) {             // T13 defer-rescale
            float mn = fmaxf(m, mx);
            float sc = __expf(m - mn);
            l *= sc;
#pragma unroll
            for (int r = 0; r < 16; r++) {
                float scr = __shfl(sc, (r & 3) + ((r >> 2) << 3) + (hv << 2));
#pragma unroll
                for (int dt = 0; dt < 8; dt++) o[dt][r] *= scr;
            }
            m = mn;
        }
        float rs = 0.f;
#pragma unroll
        for (int r = 0; r < 16; r++) { v[r] = __expf(v[r] - m); rs += v[r]; }
        rs += __shfl_xor(rs, 32);
        l += rs;

        // ---- P -> A-fragments in-register (cvt_pk + half-exchange) ----
        unsigned wd[8], pw[8];
#pragma unroll
        for (int i = 0; i < 8; i++) wd[i] = pack2(v[2 * i], v[2 * i + 1]);
#pragma unroll
        for (int i = 0; i < 8; i++) pw[i] = (unsigned)__shfl_xor((int)wd[i], 32);

#pragma unroll
        for (int ks2 = 0; ks2 < 2; ks2++) {
            union { unsigned u[4]; short8 s8; } fr;
            const int o4 = ks2 << 2;
            fr.u[0] = hv ? pw[o4 + 2] : wd[o4 + 0];
            fr.u[1] = hv ? pw[o4 + 3] : wd[o4 + 1];
            fr.u[2] = hv ? wd[o4 + 2] : pw[o4 + 0];
            fr.u[3] = hv ? wd[o4 + 3] : pw[o4 + 1];
            const int vcol = ((wave & 1) << 6) + (ks2 << 5) + (hv << 4);
#pragma unroll
            for (int dt = 0; dt < 8; dt++) {
                int row  = ((dt & 1) << 5) + l31;
                int colb = ((dt >> 1) << 7) + vcol;
                short8 vf = *(const short8*)(pV + row * 512 + (colb ^ kxor));
                o[dt] = mfma32(fr.s8, vf, o[dt]);
            }
        }
    }

    // ---- merge the two kv-half softmaxes of each q-group ----
    __syncthreads();
    if (lane < 32) {
        sML[(wave << 6) + (l31 << 1)]     = m;
        sML[(wave << 6) + (l31 << 1) + 1] = l;
    }
    __syncthreads();
    float m1 = sML[((wave ^ 1) << 6) + (l31 << 1)];
    float l1 = sML[((wave ^ 1) << 6) + (l31 << 1) + 1];
    float M  = fmaxf(m, m1);
    float e0 = __expf(m - M), e1 = __expf(m1 - M);
    float fac = e0 / (l * e0 + l1 * e1);          // own-scale / combined-denominator
    float facr[16];
#pragma unroll
    for (int r = 0; r < 16; r++)
        facr[r] = __shfl(fac, (r & 3) + ((r >> 2) << 3) + (hv << 2));
#pragma unroll
    for (int dt = 0; dt < 8; dt++)
#pragma unroll
        for (int r = 0; r < 16; r++) o[dt][r] *= facr[r];

    float* sO = (float*)smem;                     // reuse K/V space: [pair][32q][256d]
    if (wave & 1) {
#pragma unroll
        for (int dt = 0; dt < 8; dt++)
#pragma unroll
            for (int r = 0; r < 16; r++) {
                int q = (r & 3) + ((r >> 2) << 3) + (hv << 2);
                sO[((wave >> 1) << 13) + (q << 8) + (dt << 5) + l31] = o[dt][r];
            }
    }
    __syncthreads();
    if (!(wave & 1)) {
#pragma unroll
        for (int dt = 0; dt < 8; dt++)
#pragma unroll
            for (int r = 0; r < 16; r++) {
                int q = (r & 3) + ((r >> 2) << 3) + (hv << 2);
                float val = o[dt][r] + sO[((wave >> 1) << 13) + (q << 8) + (dt << 5) + l31];
                Oa[(size_t)(b * SEQ + qb + ((wave >> 1) << 5) + q) * HID
                   + head * HD + (dt << 5) + l31] = f2bf(val);
            }
    }
}

// ---------- launch ----------
extern "C" void kernel_launch(void* const* d_in, const int* in_sizes, int n_in,
                              void* d_out, int out_size, void* d_ws, size_t ws_size,
                              hipStream_t stream) {
    const float* hidden = (const float*)d_in[0];
    // d_in[1] = attention_mask: pure causal, applied analytically (exp(-1e9) == 0)
    const float* Wq = (const float*)d_in[2];
    const float* Wk = (const float*)d_in[3];
    const float* Wv = (const float*)d_in[4];
    const float* Wo = (const float*)d_in[5];
    float* out = (float*)d_out;

    char* ws = (char*)d_ws;
    u16* hid_bf = (u16*)(ws);                       // 16 MB (dead after QKV GEMM)
    u16* Wqkvt  = (u16*)(ws + (16u << 20));         // 10 MB fused [2560][2048]
    u16* Wot    = (u16*)(ws + (26u << 20));         //  8 MB
    u16* Qb     = (u16*)(ws + (34u << 20));         // 16 MB
    u16* KVb    = (u16*)(ws + (50u << 20));         //  4 MB
    u16* Ab     = (u16*)(ws + (54u << 20));         // 16 MB (end 70 MB)
    char* KS    = ws;                               //  2 MB swizzled K tiles (reuses hid_bf,
    char* VS    = ws + (2u << 20);                  //  2 MB swizzled V tiles   written post-GEMM)

    // cvt + 4 weight transposes, one launch (8192 + 72*32 = 10496 blocks)
    k_prep<<<10496, 256, 0, stream>>>(hidden, hid_bf, Wq, Wk, Wv, Wo, Wqkvt, Wot);

    // fused QKV projection: N = 2560, grid 32x20 = 640 (%8 == 0)
    k_gemm<1><<<640, 256, 0, stream>>>(hid_bf, Wqkvt, Qb, KVb, nullptr, 2048, 20);

    // hid_bf / Wqkvt regions are dead from here on
    k_post<<<512, 256, 0, stream>>>(KVb, KS, VS);   // K-rope + V transform only

    k_attn<<<512, 256, 0, stream>>>(Qb, KS, VS, Ab);

    // output projection (fp32 out): grid 32x16 = 512
    k_gemm<0><<<512, 256, 0, stream>>>(Ab, Wot, nullptr, nullptr, out, 2048, 16);
}

// Round 18
// 220.651 us; speedup vs baseline: 1.0137x; 1.0045x over previous
//
#include <hip/hip_runtime.h>
#include <hip/hip_bf16.h>

// ---------- types / helpers ----------
typedef unsigned short u16;
typedef short short8 __attribute__((ext_vector_type(8)));
typedef float f32x4 __attribute__((ext_vector_type(4)));
typedef float f32x16 __attribute__((ext_vector_type(16)));
typedef u16 u16x4 __attribute__((ext_vector_type(4)));

__device__ __forceinline__ u16 f2bf(float f) {
    unsigned int u = __float_as_uint(f);
    u += 0x7fffu + ((u >> 16) & 1u);   // round-to-nearest-even
    return (u16)(u >> 16);
}
__device__ __forceinline__ float bf2f(u16 s) {
    return __uint_as_float(((unsigned int)s) << 16);
}
// packs 2 f32 -> 2 bf16 (RNE); official intrinsic -> v_cvt_pk_bf16_f32
__device__ __forceinline__ unsigned pack2(float lo, float hi) {
    union { __hip_bfloat162 h; unsigned u; } cv;
    cv.h = __float22bfloat162_rn(make_float2(lo, hi));
    return cv.u;
}
__device__ __forceinline__ f32x4 mfma16(short8 a, short8 b, f32x4 c) {
    return __builtin_amdgcn_mfma_f32_16x16x32_bf16(a, b, c, 0, 0, 0);
}
__device__ __forceinline__ f32x16 mfma32(short8 a, short8 b, f32x16 c) {
    return __builtin_amdgcn_mfma_f32_32x32x16_bf16(a, b, c, 0, 0, 0);
}
// async global->LDS, 16B/lane; LDS dest = wave-uniform base + lane*16 (m97/m104)
__device__ __forceinline__ void gld16(const void* g, void* l) {
    __builtin_amdgcn_global_load_lds(
        (const __attribute__((address_space(1))) unsigned int*)g,
        (__attribute__((address_space(3))) unsigned int*)l, 16, 0, 0);
}

// ---------- constants ----------
#define BATCH 2
#define SEQ   2048
#define HID   2048
#define NH    8
#define HD    256
#define MROWS (BATCH * SEQ)   // 4096

// ---------- fused preprocessing: hidden cvt (blocks 0..8191) + 4 weight ----------
// transposes (blocks 8192..10495; idx%72 selects matrix/col-tile, idx/72 k-tile)
__global__ __launch_bounds__(256) void k_prep(const float* __restrict__ hidden,
                                              u16* __restrict__ hid_bf,
                                              const float* __restrict__ Wq,
                                              const float* __restrict__ Wk,
                                              const float* __restrict__ Wv,
                                              const float* __restrict__ Wo,
                                              u16* __restrict__ Wqkvt,
                                              u16* __restrict__ Wot) {
    __shared__ float tile[64][65];   // +1 pad (unused in cvt branch)
    const int bx = blockIdx.x;
    if (bx < 8192) {                 // ---- fp32 -> bf16 convert, x4 ----
        int i = (bx * 256 + threadIdx.x) * 4;
        float4 v = *(const float4*)(hidden + i);
        u16x4 o; o.x = f2bf(v.x); o.y = f2bf(v.y); o.z = f2bf(v.z); o.w = f2bf(v.w);
        *(u16x4*)(hid_bf + i) = o;
        return;
    }
    const int idx = bx - 8192;       // ---- LDS-tiled weight transpose ----
    const int cx = idx % 72, ky = idx / 72;
    const float* W; u16* Wt; int N, n0;
    if (cx < 32)      { W = Wq; Wt = Wqkvt;                       N = 2048; n0 = cx << 6; }
    else if (cx < 36) { W = Wk; Wt = Wqkvt + (size_t)2048 * 2048; N = 256;  n0 = (cx - 32) << 6; }
    else if (cx < 40) { W = Wv; Wt = Wqkvt + (size_t)2304 * 2048; N = 256;  n0 = (cx - 36) << 6; }
    else              { W = Wo; Wt = Wot;                         N = 2048; n0 = (cx - 40) << 6; }
    const int k0 = ky << 6;
    const int tr = threadIdx.x >> 6, tc = threadIdx.x & 63;
#pragma unroll
    for (int i = 0; i < 16; i++)
        tile[i * 4 + tr][tc] = W[(size_t)(k0 + i * 4 + tr) * N + n0 + tc];
    __syncthreads();
#pragma unroll
    for (int i = 0; i < 16; i++) {
        int r = i * 4 + tr;
        Wt[(size_t)(n0 + r) * 2048 + k0 + tc] = f2bf(tile[tc][r]);
    }
}

// ---------- bf16 GEMM: m97-faithful SINGLE-buffer + T2 both-sides swizzle ----------
// (r12/r15, frozen) C = A[M,K] * Bt[N,K]^T; 128x128 tile, BK=64, 4 waves.
template<int FUSEQKV>
__global__ __launch_bounds__(256) void k_gemm(const u16* __restrict__ A,
                                              const u16* __restrict__ Bt,
                                              u16* __restrict__ Cq,
                                              u16* __restrict__ Ckv,
                                              float* __restrict__ Cf,
                                              int K, int nbx) {
    const int cpx = gridDim.x >> 3;
    const int t8  = (blockIdx.x & 7) * cpx + (blockIdx.x >> 3);   // bijective (nwg%8==0)
    const int m0 = (t8 / nbx) << 7;
    const int n0 = (t8 % nbx) << 7;

    const int tid = threadIdx.x, lane = tid & 63, wave = tid >> 6;
    const int g = lane >> 4, c = lane & 15;
    const int wrow = (wave >> 1) << 6, wcol = (wave & 1) << 6;

    __shared__ __align__(16) u16 sA[128 * 64];
    __shared__ __align__(16) u16 sB[128 * 64];

    const int srow = lane >> 3;                      // 0..7 within 8-row DMA chunk
    const int scol = ((lane & 7) ^ srow) << 3;       // inverse swizzle on source
    const u16* gA = A  + (size_t)(m0 + wave * 32 + srow) * K + scol;
    const u16* gB = Bt + (size_t)(n0 + wave * 32 + srow) * K + scol;
    u16* const lA = sA + wave * 32 * 64;
    u16* const lB = sB + wave * 32 * 64;

    f32x4 acc[4][4] = {};

    for (int k0 = 0; k0 < K; k0 += 64) {
        __syncthreads();                  // prev tile fully consumed
#pragma unroll
        for (int i = 0; i < 4; i++) {
            gld16(gA + k0 + (size_t)i * 8 * K, lA + i * 8 * 64);
            gld16(gB + k0 + (size_t)i * 8 * K, lB + i * 8 * 64);
        }
        __syncthreads();                  // compiler drains vmcnt before barrier
#pragma unroll
        for (int ks = 0; ks < 2; ks++) {
            short8 aF[4], bF[4];
#pragma unroll
            for (int tt = 0; tt < 4; tt++) {
                const int ar = wrow + tt * 16 + c;
                const int br = wcol + tt * 16 + c;
                const int coff = ks * 64 + g * 16;   // byte offset within 128B row
                aF[tt] = *(const short8*)((const char*)sA + ar * 128 + (coff ^ ((ar & 7) << 4)));
                bF[tt] = *(const short8*)((const char*)sB + br * 128 + (coff ^ ((br & 7) << 4)));
            }
#pragma unroll
            for (int mt = 0; mt < 4; mt++)
#pragma unroll
                for (int ntc = 0; ntc < 4; ntc++)
                    acc[mt][ntc] = mfma16(aF[mt], bF[ntc], acc[mt][ntc]);
        }
    }

#pragma unroll
    for (int mt = 0; mt < 4; mt++)
#pragma unroll
        for (int ntc = 0; ntc < 4; ntc++)
#pragma unroll
            for (int r = 0; r < 4; r++) {
                int row = m0 + wrow + mt * 16 + g * 4 + r;
                int col = n0 + wcol + ntc * 16 + c;
                float v = acc[mt][ntc][r];
                if (FUSEQKV) {
                    if (col < 2048) Cq [(size_t)row * 2048 + col] = f2bf(v);
                    else            Ckv[(size_t)row * 512 + (col - 2048)] = f2bf(v);
                } else {
                    Cf[(size_t)row * 2048 + col] = v;
                }
            }
}

// ---------- fused post-GEMM: RoPE x8 (blocks 0..2303) + V transform (2304..2559) ----------
__global__ __launch_bounds__(256) void k_post(u16* __restrict__ Qb,
                                              const u16* __restrict__ KVb,
                                              char* __restrict__ KS,
                                              char* __restrict__ VS) {
    __shared__ u16 sT[64][72];       // [kv][d], +8 pad (vt branch only)
    const int bx = blockIdx.x;
    if (bx < 2304) {                 // ---- RoPE, vectorized x8 ----
        int idx = bx * 256 + threadIdx.x;
        const int QG = MROWS * NH * 16;    // 524288 Q groups
        if (idx < QG) {
            int row  = idx >> 7;
            int rest = idx & 127;
            int h = rest >> 4, d0 = (rest & 15) << 3;
            u16* base = Qb + (size_t)row * HID + h * HD + d0;
            int pos = row & (SEQ - 1);
            short8 lo = *(const short8*)(base);
            short8 hi = *(const short8*)(base + 128);
            short8 olo, ohi;
#pragma unroll
            for (int j = 0; j < 8; j++) {
                int d = d0 + j;
                float invf = __expf(-(float)d * (9.2103403719761836f / 128.0f));
                float ang = (float)pos * invf;
                float sn, cs; __sincosf(ang, &sn, &cs);
                float x0 = bf2f((u16)lo[j]);
                float x1 = bf2f((u16)hi[j]);
                olo[j] = (short)f2bf(x0 * cs - x1 * sn);
                ohi[j] = (short)f2bf(x1 * cs + x0 * sn);
            }
            *(short8*)(base)       = olo;
            *(short8*)(base + 128) = ohi;
        } else {
            int j0 = idx - QG;             // 65536 K groups
            int row = j0 >> 4, d0 = (j0 & 15) << 3;
            const u16* src = KVb + (size_t)row * 512 + d0;
            int pos = row & (SEQ - 1);
            short8 lo = *(const short8*)(src);
            short8 hi = *(const short8*)(src + 128);
            short8 olo, ohi;
#pragma unroll
            for (int j = 0; j < 8; j++) {
                int d = d0 + j;
                float invf = __expf(-(float)d * (9.2103403719761836f / 128.0f));
                float ang = (float)pos * invf;
                float sn, cs; __sincosf(ang, &sn, &cs);
                float x0 = bf2f((u16)lo[j]);
                float x1 = bf2f((u16)hi[j]);
                olo[j] = (short)f2bf(x0 * cs - x1 * sn);
                ohi[j] = (short)f2bf(x1 * cs + x0 * sn);
            }
            int bb = row >> 11, sr = row & 2047;
            char* obase = KS + ((size_t)bb << 20) + (size_t)(sr >> 6) * 32768 + (sr & 63) * 512;
            int xr = (sr & 31) << 4;
            *(short8*)(obase + (((d0 << 1))       ^ xr)) = olo;
            *(short8*)(obase + (((d0 << 1) + 256) ^ xr)) = ohi;
        }
        return;
    }
    // ---- V transform: KVb V-half -> VS swizzled tiles ----
    const int bid = bx - 2304;
    const int b = bid >> 7, kvt = (bid >> 2) & 31, dc = bid & 3;
    const int tr = threadIdx.x >> 6, tc = threadIdx.x & 63;
#pragma unroll
    for (int i = 0; i < 16; i++) {
        int kv = i * 4 + tr;
        sT[kv][tc] = KVb[((size_t)(b * SEQ + kvt * 64 + kv) << 9) + 256 + (dc << 6) + tc];
    }
    __syncthreads();
    char* obase = VS + ((size_t)b << 20) + (size_t)kvt * 32768;
#pragma unroll
    for (int e = 0; e < 2; e++) {
        int u = threadIdx.x * 2 + e;          // 0..511
        int dl = u >> 3, kvc = u & 7;         // d-local, kv-chunk
        union { u16 h[8]; uint4 q; } pk;
#pragma unroll
        for (int j = 0; j < 8; j++) pk.h[j] = sT[kvc * 8 + j][dl];
        int byte = dl * 512 + ((((dc << 7) + (kvc << 4))) ^ ((dl & 31) << 4));
        *(uint4*)(obase + byte) = pk.q;
    }
}

// ---------- causal GQA flash attention — r10/r13 structure (101 µs, frozen) ----------
// 512 blocks x 4 waves. Waves {0,1}: q rows [qb,qb+32), kv halves 0/1;
// waves {2,3}: q rows [qb+32,qb+64). Pair q-tile a with 31-a across the two
// per-CU block slots (balanced: 33 tile-units per CU). K/V staged via gld16.
// NOTE (r14): T14 reg-staging spills here (o[8]=128 VGPR accum). (r17):
// in-register Q-RoPE costs more in serial VALU prologue than it saves.
__global__ __launch_bounds__(256, 2) void k_attn(const u16* __restrict__ Q,
                                                 const char* __restrict__ KS,
                                                 const char* __restrict__ VS,
                                                 u16* __restrict__ Oa) {
    const int tid  = threadIdx.x;
    const int lane = tid & 63;
    const int wave = tid >> 6;
    const int l31  = lane & 31;
    const int hv   = lane >> 5;

    const int bid   = blockIdx.x;
    const int bh    = bid & 15;
    const int qpair = (bid >> 4) & 15;
    const int qidx  = (bid >> 8) ? (31 - qpair) : qpair;  // pair long+short on a CU
    const int qb    = qidx << 6;
    const int b = bh >> 3, head = bh & 7;

    __shared__ __align__(16) char smem[66560];   // K 32K | V 32K | m,l 1K
    char*  const pK  = smem;
    char*  const pV  = smem + 32768;
    float* const sML = (float*)(smem + 65536);

    // Q fragments in registers: row qg, d = 16*ks + 8*hv + j
    const int qg = qb + ((wave >> 1) << 5) + l31;
    short8 qf[16];
    {
        const u16* qptr = Q + (size_t)(b * SEQ + qg) * HID + head * HD + (hv << 3);
#pragma unroll
        for (int ks = 0; ks < 16; ks++)
            qf[ks] = *(const short8*)(qptr + (ks << 4));
    }

    f32x16 o[8] = {};
    float m = -1e30f, l = 0.f;

    const char* kgb = KS + ((size_t)b << 20);
    const char* vgb = VS + ((size_t)b << 20);
    const int   kxor  = l31 << 4;
    const char* kbase = pK + (((wave & 1) << 5) + l31) * 512;

    const int nt = qidx + 1;
    for (int t = 0; t < nt; t++) {
        __syncthreads();                          // prev tile fully consumed
#pragma unroll
        for (int i = 0; i < 8; i++) {             // 32KB K + 32KB V, DMA
            int chunk = (i << 2) + wave;
            gld16(kgb + (size_t)t * 32768 + chunk * 1024 + lane * 16, pK + chunk * 1024);
            gld16(vgb + (size_t)t * 32768 + chunk * 1024 + lane * 16, pV + chunk * 1024);
        }
        __syncthreads();                          // vmcnt drained before use

        // ---- S^T = K Q^T (32 kv x 32 q), dual accumulator chains ----
        f32x16 sv0 = {}, sv1 = {};
#pragma unroll
        for (int ks = 0; ks < 16; ks += 2) {
            short8 kf0 = *(const short8*)(kbase + (((ks << 5) + (hv << 4)) ^ kxor));
            short8 kf1 = *(const short8*)(kbase + ((((ks + 1) << 5) + (hv << 4)) ^ kxor));
            sv0 = mfma32(kf0, qf[ks], sv0);
            sv1 = mfma32(kf1, qf[ks + 1], sv1);
        }
        f32x16 s = sv0 + sv1;

        // ---- in-lane softmax for q-col l31 (16 kv values/lane) ----
        float v[16];
        float mx = -3.0e38f;
        const bool diag = (t == nt - 1);
#pragma unroll
        for (int r = 0; r < 16; r++) {
            float x = s[r] * 0.0625f;
            if (diag) {
                int kvg = (t << 6) + ((wave & 1) << 5) + (r & 3) + ((r >> 2) << 3) + (hv << 2);
                if (kvg > qg) x = -3.0e38f;       // sentinel << m-init (-1e30)
            }
            v[r] = x;
            mx = fmaxf(mx, x);
        }
        mx = fmaxf(mx, __shfl_xor(mx, 32));
        if (!__all(mx <= m + 8.0f)) {             // T13 defer-rescale
            float mn = fmaxf(m, mx);
            float sc = __expf(m - mn);
            l *= sc;
#pragma unroll
            for (int r = 0; r < 16; r++) {
                float scr = __shfl(sc, (r & 3) + ((r >> 2) << 3) + (hv << 2));
#pragma unroll
                for (int dt = 0; dt < 8; dt++) o[dt][r] *= scr;
            }
            m = mn;
        }
        float rs = 0.f;
#pragma unroll
        for (int r = 0; r < 16; r++) { v[r] = __expf(v[r] - m); rs += v[r]; }
        rs += __shfl_xor(rs, 32);
        l += rs;

        // ---- P -> A-fragments in-register (cvt_pk + half-exchange) ----
        unsigned wd[8], pw[8];
#pragma unroll
        for (int i = 0; i < 8; i++) wd[i] = pack2(v[2 * i], v[2 * i + 1]);
#pragma unroll
        for (int i = 0; i < 8; i++) pw[i] = (unsigned)__shfl_xor((int)wd[i], 32);

#pragma unroll
        for (int ks2 = 0; ks2 < 2; ks2++) {
            union { unsigned u[4]; short8 s8; } fr;
            const int o4 = ks2 << 2;
            fr.u[0] = hv ? pw[o4 + 2] : wd[o4 + 0];
            fr.u[1] = hv ? pw[o4 + 3] : wd[o4 + 1];
            fr.u[2] = hv ? wd[o4 + 2] : pw[o4 + 0];
            fr.u[3] = hv ? wd[o4 + 3] : pw[o4 + 1];
            const int vcol = ((wave & 1) << 6) + (ks2 << 5) + (hv << 4);
#pragma unroll
            for (int dt = 0; dt < 8; dt++) {
                int row  = ((dt & 1) << 5) + l31;
                int colb = ((dt >> 1) << 7) + vcol;
                short8 vf = *(const short8*)(pV + row * 512 + (colb ^ kxor));
                o[dt] = mfma32(fr.s8, vf, o[dt]);
            }
        }
    }

    // ---- merge the two kv-half softmaxes of each q-group ----
    __syncthreads();
    if (lane < 32) {
        sML[(wave << 6) + (l31 << 1)]     = m;
        sML[(wave << 6) + (l31 << 1) + 1] = l;
    }
    __syncthreads();
    float m1 = sML[((wave ^ 1) << 6) + (l31 << 1)];
    float l1 = sML[((wave ^ 1) << 6) + (l31 << 1) + 1];
    float M  = fmaxf(m, m1);
    float e0 = __expf(m - M), e1 = __expf(m1 - M);
    float fac = e0 / (l * e0 + l1 * e1);          // own-scale / combined-denominator
    float facr[16];
#pragma unroll
    for (int r = 0; r < 16; r++)
        facr[r] = __shfl(fac, (r & 3) + ((r >> 2) << 3) + (hv << 2));
#pragma unroll
    for (int dt = 0; dt < 8; dt++)
#pragma unroll
        for (int r = 0; r < 16; r++) o[dt][r] *= facr[r];

    float* sO = (float*)smem;                     // reuse K/V space: [pair][32q][256d]
    if (wave & 1) {
#pragma unroll
        for (int dt = 0; dt < 8; dt++)
#pragma unroll
            for (int r = 0; r < 16; r++) {
                int q = (r & 3) + ((r >> 2) << 3) + (hv << 2);
                sO[((wave >> 1) << 13) + (q << 8) + (dt << 5) + l31] = o[dt][r];
            }
    }
    __syncthreads();
    if (!(wave & 1)) {
#pragma unroll
        for (int dt = 0; dt < 8; dt++)
#pragma unroll
            for (int r = 0; r < 16; r++) {
                int q = (r & 3) + ((r >> 2) << 3) + (hv << 2);
                float val = o[dt][r] + sO[((wave >> 1) << 13) + (q << 8) + (dt << 5) + l31];
                Oa[(size_t)(b * SEQ + qb + ((wave >> 1) << 5) + q) * HID
                   + head * HD + (dt << 5) + l31] = f2bf(val);
            }
    }
}

// ---------- launch ----------
extern "C" void kernel_launch(void* const* d_in, const int* in_sizes, int n_in,
                              void* d_out, int out_size, void* d_ws, size_t ws_size,
                              hipStream_t stream) {
    const float* hidden = (const float*)d_in[0];
    // d_in[1] = attention_mask: pure causal, applied analytically (exp(-1e9) == 0)
    const float* Wq = (const float*)d_in[2];
    const float* Wk = (const float*)d_in[3];
    const float* Wv = (const float*)d_in[4];
    const float* Wo = (const float*)d_in[5];
    float* out = (float*)d_out;

    char* ws = (char*)d_ws;
    u16* hid_bf = (u16*)(ws);                       // 16 MB (dead after QKV GEMM)
    u16* Wqkvt  = (u16*)(ws + (16u << 20));         // 10 MB fused [2560][2048]
    u16* Wot    = (u16*)(ws + (26u << 20));         //  8 MB
    u16* Qb     = (u16*)(ws + (34u << 20));         // 16 MB
    u16* KVb    = (u16*)(ws + (50u << 20));         //  4 MB
    u16* Ab     = (u16*)(ws + (54u << 20));         // 16 MB (end 70 MB)
    char* KS    = ws;                               //  2 MB swizzled K tiles (reuses hid_bf,
    char* VS    = ws + (2u << 20);                  //  2 MB swizzled V tiles   written post-GEMM)

    // cvt + 4 weight transposes, one launch (8192 + 72*32 = 10496 blocks)
    k_prep<<<10496, 256, 0, stream>>>(hidden, hid_bf, Wq, Wk, Wv, Wo, Wqkvt, Wot);

    // fused QKV projection: N = 2560, grid 32x20 = 640 (%8 == 0)
    k_gemm<1><<<640, 256, 0, stream>>>(hid_bf, Wqkvt, Qb, KVb, nullptr, 2048, 20);

    // hid_bf / Wqkvt regions are dead from here on
    k_post<<<2560, 256, 0, stream>>>(Qb, KVb, KS, VS);   // rope + V transform

    k_attn<<<512, 256, 0, stream>>>(Qb, KS, VS, Ab);

    // output projection (fp32 out): grid 32x16 = 512
    k_gemm<0><<<512, 256, 0, stream>>>(Ab, Wot, nullptr, nullptr, out, 2048, 16);
}